// Round 9
// baseline (23.557 us; speedup 1.0000x reference)
//
#include <hip/hip_runtime.h>
#include <hip/hip_bf16.h>

#define EPS 1e-07f

#define BLOCK  256          // main kernel block (1 ray/thread)
#define NCH    64           // K-chunks (grid.y)
#define PBLOCK 64           // precompute block size

// sqrt(0.5*log2(e)) ; log2(sqrt(2*pi))
#define SQRT_HALF_LOG2E 0.84932180028801904f
#define LOG2_SQRT_2PI   1.32574806473616588f

typedef float v4f __attribute__((ext_vector_type(4)));

// ---------------------------------------------------------------------------
// Kernel 1: per-Gaussian precompute + zero d_out.
// Cross-product identity: c0 - b^2/a = (u x (p-pos))^2 / a',  a' = u^T(S/detS)u
// Group-interleaved table gG[NG_PAD][24] floats (96 B per 4-Gaussian group):
//   [0..3]=m00' [4..7]=m01' [8..11]=m11' [12..15]=cc [16..19]=pos0 [20..23]=pos1
// Padded tail groups get identity records (cc=-1e38 -> exp2 -> 0 contribution).
// ---------------------------------------------------------------------------
__global__ __launch_bounds__(PBLOCK) void precompute_gauss(
                                 const float* __restrict__ pos_raw,
                                 const float* __restrict__ conc_raw,
                                 const float* __restrict__ scale_raw,
                                 const float* __restrict__ rot_raw,
                                 const void*  __restrict__ map_size_p,
                                 float* __restrict__ gG,
                                 float* __restrict__ out,
                                 int K, int KPAD, int R)
{
    int k = blockIdx.x * blockDim.x + threadIdx.x;
    int nthreads = gridDim.x * blockDim.x;

    // Zero the output (ordered before splat_main on the same stream).
    for (int i = k; i < R; i += nthreads) out[i] = 0.0f;

    if (k >= KPAD) return;

    const int q = k >> 2, e = k & 3;
    float* rec = gG + q * 24;

    if (k >= K) {               // pad: contributes exactly 0
        rec[0  + e] = 1.0f;     // m00'
        rec[4  + e] = 0.0f;     // m01'
        rec[8  + e] = 1.0f;     // m11'
        rec[12 + e] = -1e38f;   // cc
        rec[16 + e] = 0.0f;
        rec[20 + e] = 0.0f;
        return;
    }

    // map_size may arrive as int32 or float32 single-element array.
    unsigned int msbits = *(const unsigned int*)map_size_p;
    float msf = __uint_as_float(msbits);
    const float ms = (msf >= 1e-3f && msf <= 1e9f) ? msf
                                                   : (float)(*(const int*)map_size_p);

    float pr0 = pos_raw[2*k],  pr1 = pos_raw[2*k+1];
    float pos0 = ms / (1.0f + __expf(-pr0));   // sigmoid * map_size
    float pos1 = ms / (1.0f + __expf(-pr1));

    float cr = conc_raw[k];
    float conc = fmaxf(cr, 0.0f) + __logf(1.0f + __expf(-fabsf(cr)));  // softplus

    float s0 = __expf(scale_raw[2*k]);
    float s1 = __expf(scale_raw[2*k+1]);
    float d0 = 1.0f / (s0*s0 + EPS);
    float d1 = 1.0f / (s1*s1 + EPS);

    float rot = rot_raw[k];
    float c = __cosf(rot), s = __sinf(rot);

    float m00 = c*c*d0 + s*s*d1;
    float m01 = c*s*(d0 - d1);
    float m11 = s*s*d0 + c*c*d1;

    float det    = d0 * d1;            // detS
    float invdet = 1.0f / det;
    float cc = __log2f(conc) + LOG2_SQRT_2PI - 0.5f * __log2f(det);

    rec[0  + e] = m00 * invdet;
    rec[4  + e] = m01 * invdet;
    rec[8  + e] = m11 * invdet;
    rec[12 + e] = cc;
    rec[16 + e] = pos0;
    rec[20 + e] = pos1;
}

// ---------------------------------------------------------------------------
// Kernel 2: main pairwise accumulation. Gaussian stream is wave-uniform
// (chunk = blockIdx.y) and fetched through the SCALAR pipe via forced
// s_load_dwordx4 into SGPRs — zero LDS, zero vector-memory in the loop.
//   t   = (w~ + u~1*pos0 - u~0*pos1) * rsqrt(a')
//   out+= rsqrt(a') * 2^( cc - t^2 )
// ---------------------------------------------------------------------------
__global__ __launch_bounds__(BLOCK) void splat_main(
        const float* __restrict__ p_rays,
        const float* __restrict__ u_rays,
        const float* __restrict__ gG,
        float* __restrict__ out,
        int GPC, int R)
{
    const int ray = blockIdx.x * BLOCK + threadIdx.x;

    float2 p2 = *(const float2*)(p_rays + 2*min(ray, R-1));
    float2 u2 = *(const float2*)(u_rays + 2*min(ray, R-1));
    const float p0 = p2.x, p1 = p2.y, u0 = u2.x, u1 = u2.y;

    const float qu0  = u0*u0, qu1 = 2.0f*u0*u1, qu2 = u1*u1;
    const float wt   =  SQRT_HALF_LOG2E * (u0*p1 - u1*p0);
    const float su1  =  SQRT_HALF_LOG2E * u1;
    const float nsu0 = -SQRT_HALF_LOG2E * u0;

    float acc = 0.0f;

    const float* gptr = gG + (size_t)blockIdx.y * GPC * 24;

    for (int g = 0; g < GPC; ++g) {
        v4f M00, M01, M11, CC, P0, P1;
        // Forced scalar loads: one 96B group -> 24 SGPRs. Early-clobber so
        // the address pair %6 isn't allocated into an output tuple.
        asm volatile(
            "s_load_dwordx4 %0, %6, 0x0\n\t"
            "s_load_dwordx4 %1, %6, 0x10\n\t"
            "s_load_dwordx4 %2, %6, 0x20\n\t"
            "s_load_dwordx4 %3, %6, 0x30\n\t"
            "s_load_dwordx4 %4, %6, 0x40\n\t"
            "s_load_dwordx4 %5, %6, 0x50\n\t"
            "s_waitcnt lgkmcnt(0)"
            : "=&s"(M00), "=&s"(M01), "=&s"(M11),
              "=&s"(CC),  "=&s"(P0),  "=&s"(P1)
            : "s"(gptr));

        #pragma unroll
        for (int e = 0; e < 4; ++e) {
            float a_  = fmaf(qu2, M11[e], fmaf(qu1, M01[e], qu0 * M00[e]));
            float cr_ = fmaf(nsu0, P1[e], fmaf(su1, P0[e], wt));
            float ra_ = __builtin_amdgcn_rsqf(a_);
            float t_  = cr_ * ra_;
            float ar_ = fmaf(-t_, t_, CC[e]);
            float e_  = __builtin_amdgcn_exp2f(ar_);
            acc = fmaf(ra_, e_, acc);
        }
        gptr += 24;
    }

    if (ray < R) atomicAdd(&out[ray], acc);
}

// ---------------------------------------------------------------------------
extern "C" void kernel_launch(void* const* d_in, const int* in_sizes, int n_in,
                              void* d_out, int out_size, void* d_ws, size_t ws_size,
                              hipStream_t stream)
{
    const float* pos_raw   = (const float*)d_in[0];
    const float* conc_raw  = (const float*)d_in[1];
    const float* scale_raw = (const float*)d_in[2];
    const float* rot_raw   = (const float*)d_in[3];
    const float* p_rays    = (const float*)d_in[4];
    const float* u_rays    = (const float*)d_in[5];
    const void*  map_size  = d_in[6];

    const int K = in_sizes[1];          // conc_raw is (K,)
    const int R = out_size;             // output is (R,)

    // Pad group count to a multiple of NCH so every chunk is uniform.
    const int ng_tot = (K + 3) / 4;
    const int GPC    = (ng_tot + NCH - 1) / NCH;   // groups per chunk
    const int ng_pad = GPC * NCH;
    const int KPAD   = ng_pad * 4;

    float* out = (float*)d_out;
    float* gG  = (float*)d_ws;          // ng_pad * 24 floats

    {
        dim3 grid((KPAD + PBLOCK - 1) / PBLOCK);
        precompute_gauss<<<grid, PBLOCK, 0, stream>>>(pos_raw, conc_raw, scale_raw,
                                                      rot_raw, map_size,
                                                      gG, out, K, KPAD, R);
    }
    {
        dim3 grid((R + BLOCK - 1) / BLOCK, NCH);
        splat_main<<<grid, BLOCK, 0, stream>>>(p_rays, u_rays, gG, out, GPC, R);
    }
}